// Round 11
// baseline (96.279 us; speedup 1.0000x reference)
//
#include <hip/hip_runtime.h>
#include <hip/hip_bf16.h>

// CapsuleLayer dynamic routing, MI355X. fp32 in/out.
// C=10, B=128, N=1152, IN=8, OUT=16, 3 routing iters.
//
// v9 (round 11): two-kernel split through d_ws.
//   r10 monolith (41.8 us) pays 377 MB of L2/TA W-traffic because each
//   W-read serves only G=2 b-values (LDS capacity forced G=2), plus a
//   2.5-round tail at 2 blocks/CU. The split resolves the structural
//   tension (GEMM wants B-major W-reuse; routing wants all-N per (c,b)):
//   K1 priors_gemm: block=(c, 128 n-rows, 16 b). W chunk in 32 regs reused
//     across 16 b -> W L2 traffic 47 MB (8x less than r10). No LDS. Writes
//     priors bf16 [C,B,N,OUT] to ws (47 MB, ~7.5 us write-bound).
//     g-loop unroll capped at 4: no per-g register array exists, so no
//     r9-style scratch demotion; bounds in-flight x-loads.
//   K2 routing: block per (c,b), 1280 blocks; stages its 36.9 KB bf16 slice
//     into LDS (37.5 KB -> 4 blocks/CU = 32 waves/CU occupancy), then the
//     r10-proven routing math (G=1). Priors are L3-resident from K1.
//   Precision: bf16 priors only; fp32 accum everywhere (r8-r10: absmax
//   0.0078 vs threshold 0.0172).
//   Routing identities: logits scalar per (c,b,n) (reference keepdims
//   broadcast); logit state eliminated: logit = dot(accum-out, P) each iter;
//   unnormalized softmax (|logit| <~ 30, fp32-safe).

constexpr int C = 10, B = 128, N = 1152, IN = 8, OUT = 16;

__device__ __forceinline__ unsigned packbf(float a, float b) {
    __hip_bfloat162 h = __float22bfloat162_rn(float2{a, b});  // RNE
    return *(unsigned*)&h;
}
__device__ __forceinline__ float bflo(unsigned u) { return __uint_as_float(u << 16); }
__device__ __forceinline__ float bfhi(unsigned u) { return __uint_as_float(u & 0xffff0000u); }

// ---------------- K1: priors GEMM ----------------
// grid = C * (N/128) * (B/16) = 10*9*8 = 720 blocks, 512 threads.
// Lane l: o-quad q=l&3, row-sub rsub=l>>2; wave wid covers 16 rows.
// Block covers 128 rows (8 waves x 16) x 16 b-values.
constexpr int T1 = 512;
constexpr int BT = 16;     // b per block

__global__ __launch_bounds__(T1)
void priors_gemm(const float* __restrict__ Xf, const float* __restrict__ Wf,
                 uint2* __restrict__ Pws) {
    const int t = threadIdx.x;
    const int l = t & 63;
    const int wid = t >> 6;
    const int q = l & 3;
    const int rsub = l >> 2;
    const int blk = blockIdx.x;
    const int bt = blk & 7;           // 8 b-tiles; consecutive blocks share W chunk
    const int rest = blk >> 3;
    const int nc = rest % 9;
    const int c = rest / 9;
    const int n = nc * 128 + wid * 16 + rsub;

    // W[c,n,i,q*4..+3]: one float4 per i; 16 rows x 64 B fully-consumed lines
    const float4* wr = (const float4*)(Wf + (size_t)(c * N + n) * (IN * OUT));
    float4 wv[IN];
    #pragma unroll
    for (int i = 0; i < IN; ++i) wv[i] = wr[i * 4 + q];

    #pragma unroll 4
    for (int g = 0; g < BT; ++g) {
        const int b = bt * BT + g;
        const float4* xr = (const float4*)(Xf + (size_t)(b * N + n) * IN);
        const float4 xa = xr[0], xc = xr[1];
        const float xs[8] = { xa.x, xa.y, xa.z, xa.w, xc.x, xc.y, xc.z, xc.w };
        float a0 = 0.f, a1 = 0.f, a2 = 0.f, a3 = 0.f;
        #pragma unroll
        for (int i = 0; i < IN; ++i) {
            a0 = fmaf(xs[i], wv[i].x, a0);
            a1 = fmaf(xs[i], wv[i].y, a1);
            a2 = fmaf(xs[i], wv[i].z, a2);
            a3 = fmaf(xs[i], wv[i].w, a3);
        }
        // priors[c][b][n][o] bf16, uint2 = o-quad q; wave store = 512 B contiguous
        Pws[((size_t)(c * B + b) * N + n) * 4 + q] =
            uint2{packbf(a0, a1), packbf(a2, a3)};
    }
}

// ---------------- K2: routing ----------------
// grid = C*B = 1280 blocks, 512 threads (8 waves). LDS ~37.5 KB -> 4 blocks/CU.
constexpr int T2 = 512;
constexpr int NW2 = T2 / 64;           // 8 waves
constexpr int PASSES = N / (NW2 * 16); // 9

__global__ __launch_bounds__(T2)
void routing(const uint2* __restrict__ Pws, float* __restrict__ Of) {
    __shared__ uint2 ldsP[N * 4];      // canonical [n][o-quad], 36,864 B
    __shared__ float lds_s[NW2][OUT];
    __shared__ float lds_sum[NW2];
    __shared__ float lds_out[OUT];

    const int t = threadIdx.x;
    const int l = t & 63;
    const int wid = t >> 6;
    const int q = l & 3;
    const int rsub = l >> 2;
    const int blk = blockIdx.x;        // == c*B + b; Of layout matches directly

    // ---- stage this (c,b)'s prior slice into LDS (coalesced, L3-resident) ----
    const uint2* src = Pws + (size_t)blk * (N * 4);
    #pragma unroll
    for (int k = 0; k < (N * 4) / T2; ++k)   // 9 uint2/thread
        ldsP[k * T2 + t] = src[k * T2 + t];
    __syncthreads();

    // accumulated output quad-slice; logit[p] == dot(oa_full16, P[p])
    float oa[4] = {0.f, 0.f, 0.f, 0.f};

    for (int it = 0; it < 3; ++it) {
        float s0 = 0.f, s1 = 0.f, s2 = 0.f, s3 = 0.f, ssum = 0.f;
        if (it == 0) {
            ssum = (float)PASSES;      // logits 0 -> e = 1
            #pragma unroll
            for (int p = 0; p < PASSES; ++p) {
                const int n = wid * (16 * PASSES) + p * 16 + rsub;
                const uint2 u = ldsP[n * 4 + q];
                s0 += bflo(u.x); s1 += bfhi(u.x);
                s2 += bflo(u.y); s3 += bfhi(u.y);
            }
        } else {
            #pragma unroll
            for (int p = 0; p < PASSES; ++p) {
                const int n = wid * (16 * PASSES) + p * 16 + rsub;
                const uint2 u = ldsP[n * 4 + q];
                const float p0 = bflo(u.x), p1 = bfhi(u.x);
                const float p2 = bflo(u.y), p3 = bfhi(u.y);
                // logit = dot(out_accum, P[n,:]) via quad butterfly
                float d = oa[0] * p0;
                d = fmaf(oa[1], p1, d);
                d = fmaf(oa[2], p2, d);
                d = fmaf(oa[3], p3, d);
                d += __shfl_xor(d, 1, 64);
                d += __shfl_xor(d, 2, 64);
                const float e = __expf(d);       // replicated across quad
                ssum += e;
                s0 = fmaf(e, p0, s0);
                s1 = fmaf(e, p1, s1);
                s2 = fmaf(e, p2, s2);
                s3 = fmaf(e, p3, s3);
            }
        }
        // wave reduce across 16 row-subs (masks 4..32; quad bits hold
        // replicas (ssum) / distinct o (s0..s3))
        #pragma unroll
        for (int m = 4; m < 64; m <<= 1) {
            ssum += __shfl_xor(ssum, m, 64);
            s0 += __shfl_xor(s0, m, 64);
            s1 += __shfl_xor(s1, m, 64);
            s2 += __shfl_xor(s2, m, 64);
            s3 += __shfl_xor(s3, m, 64);
        }
        if (l < 4) {                   // lane l == quad q: owns o = l*4..l*4+3
            lds_s[wid][l * 4 + 0] = s0;
            lds_s[wid][l * 4 + 1] = s1;
            lds_s[wid][l * 4 + 2] = s2;
            lds_s[wid][l * 4 + 3] = s3;
        }
        if (l == 0) lds_sum[wid] = ssum;
        __syncthreads();   // A

        // cross-wave combine + squash on t<16
        if (t < OUT) {
            float so = 0.f, S = 0.f;
            #pragma unroll
            for (int w = 0; w < NW2; ++w) { so += lds_s[w][t]; S += lds_sum[w]; }
            so /= S;                   // s_o = softmax-weighted prior sum
            float r = so * so;         // ||s||^2 via 16-lane butterfly
            r += __shfl_xor(r, 1, 64);
            r += __shfl_xor(r, 2, 64);
            r += __shfl_xor(r, 4, 64);
            r += __shfl_xor(r, 8, 64);
            const float ov = so * (r / ((1.f + r) * sqrtf(r + 1e-8f)));
            if (it == 2) Of[(size_t)blk * OUT + t] = ov;
            else         lds_out[t] = ov;
        }

        if (it < 2) {
            __syncthreads();   // B
            oa[0] += lds_out[q * 4 + 0];
            oa[1] += lds_out[q * 4 + 1];
            oa[2] += lds_out[q * 4 + 2];
            oa[3] += lds_out[q * 4 + 3];
        }
    }
}

extern "C" void kernel_launch(void* const* d_in, const int* in_sizes, int n_in,
                              void* d_out, int out_size, void* d_ws, size_t ws_size,
                              hipStream_t stream) {
    const float* X = (const float*)d_in[0];   // [B,N,IN] fp32
    const float* W = (const float*)d_in[1];   // [C,N,IN,OUT] fp32
    float* O = (float*)d_out;                 // [C,B,OUT] fp32
    uint2* P = (uint2*)d_ws;                  // priors bf16 [C,B,N,OUT] = 47.2 MB

    hipLaunchKernelGGL(priors_gemm, dim3(C * 9 * 8), dim3(T1), 0, stream, X, W, P);
    hipLaunchKernelGGL(routing, dim3(C * B), dim3(T2), 0, stream, P, O);
}